// Round 4
// baseline (795.846 us; speedup 1.0000x reference)
//
#include <hip/hip_runtime.h>
#include <stdint.h>

// Problem constants
#define N_E    1024
#define E_DIM  512
#define BATCH  16
#define HW     4096                       // 64*64
#define NROW   (BATCH * HW)               // 65536 vectors
#define ZQ_SIZE (BATCH * E_DIM * HW)
#define LOSS_OFF ZQ_SIZE
#define IDX_OFF (ZQ_SIZE + 1)

typedef _Float16 half_t;
typedef __attribute__((ext_vector_type(2)))  __fp16   fp16x2;  // cvt_pkrtz native type
typedef __attribute__((ext_vector_type(8)))  _Float16 frag8;   // 4 VGPR MFMA operand
typedef __attribute__((ext_vector_type(16))) float    accv;    // 16 AGPR accumulator

union U32H2 { fp16x2 h; uint32_t u; };

static __device__ inline uint32_t pack2(float a, float b) {
    U32H2 t; t.h = __builtin_amdgcn_cvt_pkrtz(a, b); return t.u;
}

// Async global->LDS DMA, 16B per lane. LDS dest = wave-uniform base + lane*16.
static __device__ __forceinline__ void dma16(const void* g, void* l) {
    __builtin_amdgcn_global_load_lds(
        (const __attribute__((address_space(1))) void*)g,
        (__attribute__((address_space(3))) void*)l,
        16, 0, 0);
}

// ---------------------------------------------------------------------------
// Tile image format (B / codebook side), one tile = 128 codes x 32 k, 16 KiB:
//   per row: 128 B = 8 slots of 16 B. Logical: hi-f16 slots 0..3 (slot s holds
//   k = s*8..s*8+7 as 4 dwords, dword = (hi_{k+1}<<16)|hi_k), lo-f16 slots 4..7.
//   Physical slot = logical ^ (row & 7): a frag read (32 consecutive rows, fixed
//   logical slot) hits 8 distinct slots per 8-lane group (b128 floor), and
//   global_load_lds can stage the tile linearly. A-tiles use the same format,
//   built on the fly in LDS by the argmin kernel.
// ---------------------------------------------------------------------------
// Kernel 1: codebook prep.
//   blocks [0,128)   : pack one (jt,ks) codebook tile -> cbP (lives in d_out!)
//   blocks [128,640) : codebook transpose (ct) + code norms (cn)
__global__ void k_pack(const float* __restrict__ cb,
                       uint32_t* __restrict__ cbP,
                       float* __restrict__ cn,
                       float* __restrict__ ct) {
    __shared__ float tsh[32][33];
    int bidx = blockIdx.x;
    int tid  = threadIdx.x;

    if (bidx < 128) {
        // ---- codebook pack: tile (jt, ks); thread's 4 elems are consecutive k
        int jt = bidx >> 4, ks = bidx & 15;
        int kq = tid & 7, jb = tid >> 3;
        uint32_t* tile = cbP + (size_t)bidx * 4096;
        int sH = kq >> 1, o = (kq & 1) * 2;
        #pragma unroll
        for (int r = 0; r < 4; r++) {
            int j = jb + 32 * r;
            float4 v = *(const float4*)(cb + (size_t)(jt * 128 + j) * E_DIM + ks * 32 + kq * 4);
            uint32_t H01 = pack2(v.x, v.y);
            uint32_t H23 = pack2(v.z, v.w);
            U32H2 h01; h01.u = H01; U32H2 h23; h23.u = H23;
            uint32_t L01 = pack2(v.x - (float)h01.h.x, v.y - (float)h01.h.y);
            uint32_t L23 = pack2(v.z - (float)h23.h.x, v.w - (float)h23.h.y);
            int dH = ((sH)     ^ (j & 7)) * 4 + o;
            int dL = ((sH + 4) ^ (j & 7)) * 4 + o;
            *(uint2*)(tile + j * 32 + dH) = make_uint2(H01, H23);
            *(uint2*)(tile + j * 32 + dL) = make_uint2(L01, L23);
        }
    } else {
        // ---- ct transpose (512 blocks) + cn norms (first 256) ----
        int pb = bidx - 128;
        int tx = tid & 31, ty = tid >> 5;
        int jtp = pb & 31, ctl = pb >> 5;
        int j0 = jtp * 32, c0 = ctl * 32;
        #pragma unroll
        for (int i = 0; i < 4; i++) {
            int row = ty + i * 8;
            tsh[row][tx] = cb[(size_t)(j0 + row) * E_DIM + c0 + tx];
        }
        __syncthreads();
        #pragma unroll
        for (int i = 0; i < 4; i++) {
            int row = ty + i * 8;
            ct[(size_t)(c0 + row) * N_E + j0 + tx] = tsh[tx][row];
        }
        if (pb < 256) {
            int lane = tid & 63;
            int wvid = tid >> 6;
            int j = pb * 4 + wvid;
            const float* rowp = cb + (size_t)j * E_DIM;
            float s = 0.f;
            #pragma unroll
            for (int k = 0; k < E_DIM; k += 64) {
                float v = rowp[k + lane];
                s += v * v;
            }
            #pragma unroll
            for (int m = 32; m >= 1; m >>= 1) s += __shfl_xor(s, m);
            if (lane == 0) cn[j] = s;
        }
    }
}

// ---------------------------------------------------------------------------
// Kernel 2: MFMA distance argmin. Grid 512 (2 blocks/CU). Block = 128 rows x
// ALL 1024 codes, jt-outer (8) x ks-inner (16) = 128 phases. Per phase:
//   BSTAGE(pn): 4x dma16 of pre-packed B tile          (vmem, counted)
//   vmcnt(4):   phase pn's A f32 regs landed (issued 1 phase ago)
//   ACONV(pn):  in-register f32->hi/lo f16 split, ds_write swizzled A tile
//   ALOAD(pn+1): 16 coalesced scalar z loads -> regs   (vmem, in flight)
//   frag ds_reads(p) + 24 MFMA (setprio-wrapped)
//   lgkmcnt(0) (reads+writes drained)  vmcnt(16) (B(pn) landed)  s_barrier
// z re-reads across jt hit L3 (512 blocks x 256KB = 128MB resident).
// Waves (wm,wg): wm = row half, wg = CODE half -- wg=0 and wg=1 waves cover
// DISJOINT code subsets, so their per-row winners MUST be merged at the end
// (LDS combine; round-1..3 bug was both wg waves storing to the same row).
__global__ __launch_bounds__(256, 2) void k_argmin_mfma(
        const float* __restrict__ z,
        const uint32_t* __restrict__ cbP,
        const float* __restrict__ cn,
        uint32_t* __restrict__ bestIdx) {
    __shared__ uint32_t lds[16384];   // 2 bufs x (A 16KiB | B 16KiB) = 64 KiB

    int tid  = threadIdx.x;
    int lane = tid & 63;
    int l31  = lane & 31;
    int lh   = lane >> 5;
    int wm   = (tid >> 6) & 1;   // wave m-group (rows)
    int wg   = tid >> 7;         // wave n-group (codes)
    int wid  = tid >> 6;

    int n0  = blockIdx.x * 128;
    int b   = n0 >> 12, hw0 = n0 & 4095;

    // A-staging thread mapping: row = tid&127 (lane-consecutive -> coalesced),
    // khalf = tid>>7 selects k 0..15 / 16..31 of the 32-k phase chunk.
    int arow  = tid & 127;
    int khalf = tid >> 7;
    const float* zBase = z + (size_t)b * E_DIM * HW + hw0 + arow;

    const char* cT  = (const char*)cbP;
    int uoff  = wid * 4096;          // wave-uniform LDS byte offset (B quarter)
    int goffB = uoff + lane * 16;    // per-lane global byte offset (B)

    // preload code norms for all 8 j-tiles; pin before the counted-vmcnt loop
    float cnv[16];
    #pragma unroll
    for (int j = 0; j < 8; j++) {
        cnv[2 * j]     = cn[j * 128 + wg * 64 + l31];
        cnv[2 * j + 1] = cn[j * 128 + wg * 64 + 32 + l31];
    }
    #pragma unroll
    for (int q = 0; q < 16; q++) asm volatile("" :: "v"(cnv[q]));

    accv acc[2][2];
    #pragma unroll
    for (int mt = 0; mt < 2; mt++)
        #pragma unroll
        for (int nt = 0; nt < 2; nt++)
            #pragma unroll
            for (int i = 0; i < 16; i++) acc[mt][nt][i] = 0.f;

    float bv[2][16];
    int   bi[2][16];
    #pragma unroll
    for (int mt = 0; mt < 2; mt++)
        #pragma unroll
        for (int r = 0; r < 16; r++) { bv[mt][r] = 1e30f; bi[mt][r] = 0; }

    float rA[16];

    // issue 16 coalesced scalar loads of phase q's A chunk (channels (q&15)*32..)
    #define ALOAD(q) do {                                                      \
        int c0_ = ((q) & 15) * 32 + khalf * 16;                                \
        _Pragma("unroll")                                                      \
        for (int i = 0; i < 16; i++)                                           \
            rA[i] = zBase[(size_t)(c0_ + i) * HW];                             \
    } while (0)

    // convert rA (phase q's data) to hi/lo f16 and ds_write swizzled A tile
    #define ACONV(q) do {                                                      \
        uint32_t* at_ = lds + ((q) & 1) * 8192;                                \
        int sw_ = arow & 7;                                                    \
        uint32_t h_[8], l_[8];                                                 \
        _Pragma("unroll")                                                      \
        for (int i2 = 0; i2 < 8; i2++) {                                       \
            uint32_t H = pack2(rA[2 * i2], rA[2 * i2 + 1]);                    \
            U32H2 hh; hh.u = H;                                                \
            uint32_t L = pack2(rA[2 * i2]     - (float)hh.h.x,                 \
                               rA[2 * i2 + 1] - (float)hh.h.y);                \
            h_[i2] = H; l_[i2] = L;                                            \
        }                                                                      \
        int s0_ = khalf * 2;                                                   \
        *(uint4*)&at_[arow * 32 + (((s0_    ) ^ sw_) << 2)] =                  \
            make_uint4(h_[0], h_[1], h_[2], h_[3]);                            \
        *(uint4*)&at_[arow * 32 + (((s0_ + 1) ^ sw_) << 2)] =                  \
            make_uint4(h_[4], h_[5], h_[6], h_[7]);                            \
        *(uint4*)&at_[arow * 32 + (((s0_ + 4) ^ sw_) << 2)] =                  \
            make_uint4(l_[0], l_[1], l_[2], l_[3]);                            \
        *(uint4*)&at_[arow * 32 + (((s0_ + 5) ^ sw_) << 2)] =                  \
            make_uint4(l_[4], l_[5], l_[6], l_[7]);                            \
    } while (0)

    // dma B tile q (pre-packed) into buf[q&1]'s B region
    #define BSTAGE(q) do {                                                     \
        char* lb_ = (char*)lds + ((q) & 1) * 32768 + 16384 + uoff;             \
        const char* gb_ = cT + (size_t)(q) * 16384 + goffB;                    \
        dma16(gb_,        lb_);                                                \
        dma16(gb_ + 1024, lb_ + 1024);                                         \
        dma16(gb_ + 2048, lb_ + 2048);                                         \
        dma16(gb_ + 3072, lb_ + 3072);                                         \
    } while (0)

    // ---- prologue: phase 0 staged, phase 1's A loads in flight ----
    ALOAD(0);                                              // A0 x16
    BSTAGE(0);                                             // +B0 x4
    asm volatile("s_waitcnt vmcnt(4)" ::: "memory");       // A0 landed
    ACONV(0);
    ALOAD(1);                                              // +A1 x16
    asm volatile("s_waitcnt lgkmcnt(0)" ::: "memory");
    asm volatile("s_waitcnt vmcnt(16)" ::: "memory");      // B0 landed
    __builtin_amdgcn_s_barrier();

    #pragma unroll
    for (int jt = 0; jt < 8; jt++) {
        #pragma unroll 1
        for (int ks = 0; ks < 16; ks++) {
            int p = jt * 16 + ks, pn = p + 1;
            if (pn < 128) {
                BSTAGE(pn);                                          // +4
                asm volatile("s_waitcnt vmcnt(4)" ::: "memory");     // A(pn) in regs
                ACONV(pn);                                           // ds_write buf[pn&1]
                if (pn < 127) ALOAD(pn + 1);                         // +16
            }

            const uint32_t* A = lds + (p & 1) * 8192;
            const uint32_t* B = A + 4096;
            __builtin_amdgcn_s_setprio(1);
            #pragma unroll
            for (int ks2 = 0; ks2 < 2; ks2++) {
                int s = ks2 * 2 + lh;   // logical hi slot (k = s*8 .. s*8+7)
                frag8 ah[2], al[2], bh[2], bl[2];
                #pragma unroll
                for (int mt = 0; mt < 2; mt++) {
                    int row = wm * 64 + mt * 32 + l31;
                    int sw = row & 7;
                    ah[mt] = *(const frag8*)&A[row * 32 + ((s ^ sw) << 2)];
                    al[mt] = *(const frag8*)&A[row * 32 + (((s + 4) ^ sw) << 2)];
                }
                #pragma unroll
                for (int nt = 0; nt < 2; nt++) {
                    int n = wg * 64 + nt * 32 + l31;
                    int sw = n & 7;
                    bh[nt] = *(const frag8*)&B[n * 32 + ((s ^ sw) << 2)];
                    bl[nt] = *(const frag8*)&B[n * 32 + (((s + 4) ^ sw) << 2)];
                }
                #pragma unroll
                for (int mt = 0; mt < 2; mt++)
                    #pragma unroll
                    for (int nt = 0; nt < 2; nt++)
                        acc[mt][nt] = __builtin_amdgcn_mfma_f32_32x32x16_f16(
                            ah[mt], bh[nt], acc[mt][nt], 0, 0, 0);
                #pragma unroll
                for (int mt = 0; mt < 2; mt++)
                    #pragma unroll
                    for (int nt = 0; nt < 2; nt++)
                        acc[mt][nt] = __builtin_amdgcn_mfma_f32_32x32x16_f16(
                            ah[mt], bl[nt], acc[mt][nt], 0, 0, 0);
                #pragma unroll
                for (int mt = 0; mt < 2; mt++)
                    #pragma unroll
                    for (int nt = 0; nt < 2; nt++)
                        acc[mt][nt] = __builtin_amdgcn_mfma_f32_32x32x16_f16(
                            al[mt], bh[nt], acc[mt][nt], 0, 0, 0);
            }
            __builtin_amdgcn_s_setprio(0);
            // drain frag reads AND staged ds_writes before any wave can pass
            // the barrier and overwrite / read these buffers
            asm volatile("s_waitcnt lgkmcnt(0)" ::: "memory");
            if (pn < 128) {
                if (pn < 127) asm volatile("s_waitcnt vmcnt(16)" ::: "memory");
                else          asm volatile("s_waitcnt vmcnt(0)"  ::: "memory");
                __builtin_amdgcn_s_barrier();
            }
        }
        // ---- fold j-tile jt into running per-lane best; reset acc ----
        {
            float c0 = cnv[2 * jt], c1 = cnv[2 * jt + 1];
            int j0i = jt * 128 + wg * 64 + l31;
            int j1i = j0i + 32;
            #pragma unroll
            for (int mt = 0; mt < 2; mt++)
                #pragma unroll
                for (int r = 0; r < 16; r++) {
                    float d0 = c0 - 2.f * acc[mt][0][r];
                    float d1 = c1 - 2.f * acc[mt][1][r];
                    float v; int ix;
                    if (d1 < d0) { v = d1; ix = j1i; } else { v = d0; ix = j0i; }
                    if (v < bv[mt][r]) { bv[mt][r] = v; bi[mt][r] = ix; }
                    acc[mt][0][r] = 0.f; acc[mt][1][r] = 0.f;
                }
        }
    }

    // ---- per-wave 32-lane argmin, then cross-wave (wg) combine via LDS.
    // wg=0/wg=1 waves hold argmins over DISJOINT code halves for the SAME
    // rows: pack (mono-float-bits<<32 | idx) so u64-min = (min dist, min idx),
    // write to red[wg][row], barrier, threads 0..127 merge + single store.
    // red lives in buf0's A-region, provably dead after the last barrier.
    unsigned long long* red = (unsigned long long*)lds;
    #pragma unroll
    for (int mt = 0; mt < 2; mt++)
        #pragma unroll
        for (int r = 0; r < 16; r++) {
            float v = bv[mt][r]; int ix = bi[mt][r];
            #pragma unroll
            for (int m = 1; m <= 16; m <<= 1) {
                float ov = __shfl_xor(v, m);
                int   oi = __shfl_xor(ix, m);
                if (ov < v || (ov == v && oi < ix)) { v = ov; ix = oi; }
            }
            if (l31 == r) {
                int row = wm * 64 + mt * 32 + (r & 3) + 8 * (r >> 2) + 4 * lh;
                uint32_t s = __float_as_uint(v);
                uint32_t k32 = (s & 0x80000000u) ? ~s : (s | 0x80000000u);
                red[wg * 128 + row] =
                    ((unsigned long long)k32 << 32) | (uint32_t)ix;
            }
        }
    __syncthreads();
    if (tid < 128) {
        unsigned long long k0 = red[tid], k1 = red[128 + tid];
        unsigned long long k = (k1 < k0) ? k1 : k0;
        bestIdx[n0 + tid] = (uint32_t)k;
    }
    #undef ALOAD
    #undef ACONV
    #undef BSTAGE
}

// ---------------------------------------------------------------------------
// Kernel 3: gather z_q, straight-through output, per-block loss partials.
__global__ void k_gather_loss(const float* __restrict__ z,
                              const float* __restrict__ ct,
                              const uint32_t* __restrict__ bestIdx,
                              float* __restrict__ out,
                              float* __restrict__ pl) {
    int g = blockIdx.x * blockDim.x + threadIdx.x;
    int w4 = g & 1023;
    int bc = g >> 10;
    int c  = bc & 511;
    int b  = bc >> 9;
    int n4 = b * 1024 + w4;

    uint4 iv = *(const uint4*)(bestIdx + (size_t)n4 * 4);

    const float* ctc = ct + (size_t)c * N_E;
    float4 zq;
    zq.x = ctc[iv.x]; zq.y = ctc[iv.y]; zq.z = ctc[iv.z]; zq.w = ctc[iv.w];
    float4 zv = *(const float4*)(z + (size_t)g * 4);

    float4 d;
    d.x = zq.x - zv.x; d.y = zq.y - zv.y; d.z = zq.z - zv.z; d.w = zq.w - zv.w;
    float4 o;
    o.x = zv.x + d.x; o.y = zv.y + d.y; o.z = zv.z + d.z; o.w = zv.w + d.w;
    *(float4*)(out + (size_t)g * 4) = o;

    float ls = d.x * d.x + d.y * d.y + d.z * d.z + d.w * d.w;
    #pragma unroll
    for (int m = 32; m >= 1; m >>= 1) ls += __shfl_xor(ls, m);

    __shared__ float wsum[4];
    int lane = threadIdx.x & 63, wvid = threadIdx.x >> 6;
    if (lane == 0) wsum[wvid] = ls;
    __syncthreads();
    if (threadIdx.x == 0)
        pl[blockIdx.x] = wsum[0] + wsum[1] + wsum[2] + wsum[3];

    if (c == 0) {
        float* ip = out + IDX_OFF + (size_t)n4 * 4;
        ip[0] = (float)iv.x; ip[1] = (float)iv.y;
        ip[2] = (float)iv.z; ip[3] = (float)iv.w;
    }
}

// ---------------------------------------------------------------------------
// Kernel 4: reduce 8192 partials -> loss
__global__ void k_final(const float* __restrict__ pl, float* __restrict__ out) {
    float s = 0.f;
    for (int i = threadIdx.x; i < 8192; i += 256) s += pl[i];
    #pragma unroll
    for (int m = 32; m >= 1; m >>= 1) s += __shfl_xor(s, m);
    __shared__ float wsum[4];
    int lane = threadIdx.x & 63, wvid = threadIdx.x >> 6;
    if (lane == 0) wsum[wvid] = s;
    __syncthreads();
    if (threadIdx.x == 0) {
        float tot = wsum[0] + wsum[1] + wsum[2] + wsum[3];
        out[LOSS_OFF] = 1.25f * tot / (float)ZQ_SIZE;
    }
}

// ---------------------------------------------------------------------------
extern "C" void kernel_launch(void* const* d_in, const int* in_sizes, int n_in,
                              void* d_out, int out_size, void* d_ws, size_t ws_size,
                              hipStream_t stream) {
    (void)in_sizes; (void)n_in; (void)out_size; (void)ws_size;
    const float* z  = (const float*)d_in[0];
    const float* cb = (const float*)d_in[1];
    float* out = (float*)d_out;

    // Workspace: 2.39 MiB total -- within the 2.63 MiB the previous passing
    // kernel already proved available. No large scratch anywhere.
    float* cn = (float*)d_ws + 16;                       // 1024 f   (4 KiB)
    float* ct = cn + 1024;                               // 512x1024 f (2 MiB)
    uint32_t* bestIdx = (uint32_t*)(ct + 512 * 1024);    // 65536 u32 (256 KiB)
    float* pl = (float*)(bestIdx + NROW);                // 8192 f   (32 KiB)

    // Pre-packed codebook tiles (2 MiB) live in the FIRST 2 MiB of d_out:
    // written by k_pack, consumed by k_argmin, then overwritten by k_gather.
    uint32_t* cbP = (uint32_t*)d_out;

    k_pack<<<640, 256, 0, stream>>>(cb, cbP, cn, ct);
    k_argmin_mfma<<<512, 256, 0, stream>>>(z, cbP, cn, bestIdx);
    k_gather_loss<<<ZQ_SIZE / 4 / 256, 256, 0, stream>>>(z, ct, bestIdx, out, pl);
    k_final<<<1, 256, 0, stream>>>(pl, out);
}

// Round 6
// 493.034 us; speedup vs baseline: 1.6142x; 1.6142x over previous
//
#include <hip/hip_runtime.h>
#include <stdint.h>

// Problem constants
#define N_E    1024
#define E_DIM  512
#define BATCH  16
#define HW     4096                       // 64*64
#define NROW   (BATCH * HW)               // 65536 vectors
#define ZQ_SIZE (BATCH * E_DIM * HW)
#define LOSS_OFF ZQ_SIZE
#define IDX_OFF (ZQ_SIZE + 1)

typedef _Float16 half_t;
typedef __attribute__((ext_vector_type(2)))  __fp16   fp16x2;  // cvt_pkrtz native type
typedef __attribute__((ext_vector_type(8)))  _Float16 frag8;   // 4 VGPR MFMA operand
typedef __attribute__((ext_vector_type(16))) float    accv;    // 16 AGPR accumulator

union U32H2 { fp16x2 h; uint32_t u; };

static __device__ inline uint32_t pack2(float a, float b) {
    U32H2 t; t.h = __builtin_amdgcn_cvt_pkrtz(a, b); return t.u;
}

// Async global->LDS DMA, 16B per lane. LDS dest = wave-uniform base + lane*16.
static __device__ __forceinline__ void dma16(const void* g, void* l) {
    __builtin_amdgcn_global_load_lds(
        (const __attribute__((address_space(1))) void*)g,
        (__attribute__((address_space(3))) void*)l,
        16, 0, 0);
}

// ---------------------------------------------------------------------------
// Tile image format (verified on HW in round 4): one tile = R rows x 32 k,
// row = 128 B = 8 slots of 16 B. Logical slot s (0..3 = hi-f16, k=s*8..s*8+7;
// 4..7 = lo-f16), dword d holds elements 2d,2d+1 as (f16(k+1)<<16 | f16(k)).
// Physical slot = logical ^ (row & 7): frag ds_read_b128 (32 consecutive rows,
// fixed logical slot) hits 8 distinct slots per 8-lane group (conflict floor),
// and global_load_lds can stage the tile linearly.
//
// cbP tile ORDER is ks-major: tile index t = ks*8 + jt  (matches the argmin
// kernel's phase index p = ks*8 + jt EXACTLY -- round-5 bug was jt-major pack
// order read with a ks-major phase index, i.e. scrambled codebook).
// ---------------------------------------------------------------------------
// Kernel 1: codebook prep.
//   blocks [0,128)   : pack one (ks,jt) codebook tile -> cbP (lives in d_out!)
//   blocks [128,640) : codebook transpose (ct) + code norms (cn)
__global__ void k_pack(const float* __restrict__ cb,
                       uint32_t* __restrict__ cbP,
                       float* __restrict__ cn,
                       float* __restrict__ ct) {
    __shared__ float tsh[32][33];
    int bidx = blockIdx.x;
    int tid  = threadIdx.x;

    if (bidx < 128) {
        // ---- codebook pack: tile index bidx = ks*8 + jt (ks-major!) ----
        int jt = bidx & 7, ks = bidx >> 3;
        int kq = tid & 7, jb = tid >> 3;
        uint32_t* tile = cbP + (size_t)bidx * 4096;
        int sH = kq >> 1, o = (kq & 1) * 2;
        #pragma unroll
        for (int r = 0; r < 4; r++) {
            int j = jb + 32 * r;
            float4 v = *(const float4*)(cb + (size_t)(jt * 128 + j) * E_DIM + ks * 32 + kq * 4);
            uint32_t H01 = pack2(v.x, v.y);
            uint32_t H23 = pack2(v.z, v.w);
            U32H2 h01; h01.u = H01; U32H2 h23; h23.u = H23;
            uint32_t L01 = pack2(v.x - (float)h01.h.x, v.y - (float)h01.h.y);
            uint32_t L23 = pack2(v.z - (float)h23.h.x, v.w - (float)h23.h.y);
            int dH = ((sH)     ^ (j & 7)) * 4 + o;
            int dL = ((sH + 4) ^ (j & 7)) * 4 + o;
            *(uint2*)(tile + j * 32 + dH) = make_uint2(H01, H23);
            *(uint2*)(tile + j * 32 + dL) = make_uint2(L01, L23);
        }
    } else {
        // ---- ct transpose (512 blocks) + cn norms (first 256) ----
        int pb = bidx - 128;
        int tx = tid & 31, ty = tid >> 5;
        int jtp = pb & 31, ctl = pb >> 5;
        int j0 = jtp * 32, c0 = ctl * 32;
        #pragma unroll
        for (int i = 0; i < 4; i++) {
            int row = ty + i * 8;
            tsh[row][tx] = cb[(size_t)(j0 + row) * E_DIM + c0 + tx];
        }
        __syncthreads();
        #pragma unroll
        for (int i = 0; i < 4; i++) {
            int row = ty + i * 8;
            ct[(size_t)(c0 + row) * N_E + j0 + tx] = tsh[tx][row];
        }
        if (pb < 256) {
            int lane = tid & 63;
            int wvid = tid >> 6;
            int j = pb * 4 + wvid;
            const float* rowp = cb + (size_t)j * E_DIM;
            float s = 0.f;
            #pragma unroll
            for (int k = 0; k < E_DIM; k += 64) {
                float v = rowp[k + lane];
                s += v * v;
            }
            #pragma unroll
            for (int m = 32; m >= 1; m >>= 1) s += __shfl_xor(s, m);
            if (lane == 0) cn[j] = s;
        }
    }
}

// ---------------------------------------------------------------------------
// Kernel 2: MFMA distance argmin. Grid 1024 (1 block/CU, 8 waves), 64 rows.
// Prologue: pack the block's ENTIRE 64x512 z slice into a 128 KiB LDS A image
// (16 chunks x 8 KiB, hi/lo f16, swizzled) -- z is read from HBM exactly ONCE.
// Main loop: ks-outer (16 chunks), jt-inner unrolled (8 code tiles):
//   per phase p = ks*8+jt: vmcnt(2) (B(p) landed, B(p+1) in flight) -> barrier
//   -> [jt==0: load chunk's A frags to regs, held across all 8 jt] ->
//   B frag reads + 6 MFMA into acc[jt] (STATIC index; full dot product
//   accumulates across ks) -> lgkmcnt(0) -> barrier -> BSTAGE(p+2).
// acc[8] = 128 AGPRs; total regs ~200 -> no scratch spill (round-4 lesson).
// End: single fold (argmin over jt in-registers, 32-lane butterfly, cross-wg
// LDS combine with packed u64 keys -- the round-3 fix, kept verbatim).
__global__ __launch_bounds__(512, 2) void k_argmin_mfma(
        const float* __restrict__ z,
        const uint32_t* __restrict__ cbP,
        const float* __restrict__ cn,
        uint32_t* __restrict__ bestIdx) {
    // A image: dwords [0, 32768) = 16 chunks * 2048; B: [32768, 40960), 2 bufs
    __shared__ uint32_t lds[40960];   // 160 KiB exactly

    int tid  = threadIdx.x;
    int lane = tid & 63;
    int l31  = lane & 31;
    int lh   = lane >> 5;
    int wid  = tid >> 6;         // wave 0..7
    int wm   = wid & 1;          // row half (32 rows)
    int wg   = wid >> 1;         // code quarter (32 codes of the 128-tile)

    int n0 = blockIdx.x * 64;
    int b  = n0 >> 12, hw0 = n0 & 4095;

    // ---- prologue: pack A (64 rows x 512 ch) into LDS, read z ONCE ----
    {
        int r  = tid & 63;       // row (lane-consecutive -> coalesced loads)
        int kg = tid >> 6;       // 64-channel group
        const float* zB = z + (size_t)b * E_DIM * HW + hw0 + r;
        #pragma unroll
        for (int g = 0; g < 16; g++) {
            int ch0 = kg * 64 + g * 4;
            float v0 = zB[(size_t)(ch0    ) * HW];
            float v1 = zB[(size_t)(ch0 + 1) * HW];
            float v2 = zB[(size_t)(ch0 + 2) * HW];
            float v3 = zB[(size_t)(ch0 + 3) * HW];
            uint32_t H01 = pack2(v0, v1);
            uint32_t H23 = pack2(v2, v3);
            U32H2 h01; h01.u = H01; U32H2 h23; h23.u = H23;
            uint32_t L01 = pack2(v0 - (float)h01.h.x, v1 - (float)h01.h.y);
            uint32_t L23 = pack2(v2 - (float)h23.h.x, v3 - (float)h23.h.y);
            int chunk = ch0 >> 5;
            int kq = (ch0 & 31) >> 2;
            uint32_t* base = lds + chunk * 2048 + r * 32;
            int o = (kq & 1) * 2, sH = kq >> 1, sw = r & 7;
            *(uint2*)&base[(((sH    ) ^ sw) << 2) + o] = make_uint2(H01, H23);
            *(uint2*)&base[(((sH + 4) ^ sw) << 2) + o] = make_uint2(L01, L23);
        }
    }
    __syncthreads();   // A image complete & visible; vmcnt drained to 0

    accv acc[8];
    #pragma unroll
    for (int j = 0; j < 8; j++)
        #pragma unroll
        for (int i = 0; i < 16; i++) acc[j][i] = 0.f;

    int uoffB = wid * 2048;      // wave's 2 KiB slice of a 16 KiB B tile
    // stage B tile q (= phase q, ks-major order) into buf[q&1]
    #define BSTAGE(q) do {                                                     \
        char* lb_ = (char*)(lds + 32768) + ((q) & 1) * 16384 + uoffB;          \
        const char* gb_ = (const char*)cbP + (size_t)(q) * 16384               \
                          + uoffB + lane * 16;                                 \
        dma16(gb_,        lb_);                                                \
        dma16(gb_ + 1024, lb_ + 1024);                                         \
    } while (0)

    BSTAGE(0);
    BSTAGE(1);

    int arow = wm * 32 + l31, asw = arow & 7;
    int nn   = wg * 32 + l31, nsw = nn & 7;

    #pragma unroll 1
    for (int ks = 0; ks < 16; ks++) {
        frag8 ah0, al0, ah1, al1;   // chunk ks A frags, live across 8 jt phases
        #pragma unroll
        for (int jt = 0; jt < 8; jt++) {
            int p = ks * 8 + jt;
            if (jt == 7 && ks == 15)
                asm volatile("s_waitcnt vmcnt(0)" ::: "memory");
            else
                asm volatile("s_waitcnt vmcnt(2)" ::: "memory");
            __builtin_amdgcn_s_barrier();

            if (jt == 0) {
                const uint32_t* Ac = lds + ks * 2048 + arow * 32;
                int s0 = lh, s1 = 2 + lh;
                ah0 = *(const frag8*)&Ac[((s0 ^ asw) << 2)];
                al0 = *(const frag8*)&Ac[(((s0 + 4) ^ asw) << 2)];
                ah1 = *(const frag8*)&Ac[((s1 ^ asw) << 2)];
                al1 = *(const frag8*)&Ac[(((s1 + 4) ^ asw) << 2)];
            }
            const uint32_t* Bb = lds + 32768 + (p & 1) * 4096 + nn * 32;
            frag8 bh0 = *(const frag8*)&Bb[(((    lh) ^ nsw) << 2)];
            frag8 bl0 = *(const frag8*)&Bb[(((4 + lh) ^ nsw) << 2)];
            frag8 bh1 = *(const frag8*)&Bb[(((2 + lh) ^ nsw) << 2)];
            frag8 bl1 = *(const frag8*)&Bb[(((6 + lh) ^ nsw) << 2)];

            __builtin_amdgcn_s_setprio(1);
            acc[jt] = __builtin_amdgcn_mfma_f32_32x32x16_f16(ah0, bh0, acc[jt], 0, 0, 0);
            acc[jt] = __builtin_amdgcn_mfma_f32_32x32x16_f16(ah0, bl0, acc[jt], 0, 0, 0);
            acc[jt] = __builtin_amdgcn_mfma_f32_32x32x16_f16(al0, bh0, acc[jt], 0, 0, 0);
            acc[jt] = __builtin_amdgcn_mfma_f32_32x32x16_f16(ah1, bh1, acc[jt], 0, 0, 0);
            acc[jt] = __builtin_amdgcn_mfma_f32_32x32x16_f16(ah1, bl1, acc[jt], 0, 0, 0);
            acc[jt] = __builtin_amdgcn_mfma_f32_32x32x16_f16(al1, bh1, acc[jt], 0, 0, 0);
            __builtin_amdgcn_s_setprio(0);

            // drain this phase's ds_reads before any wave can pass the barrier
            // and DMA-overwrite the buffer (raw s_barrier does not drain DS)
            asm volatile("s_waitcnt lgkmcnt(0)" ::: "memory");
            __builtin_amdgcn_s_barrier();
            if (jt < 6 || ks < 15) BSTAGE(p + 2);
        }
    }
    #undef BSTAGE

    // ---- final fold: per-lane argmin over jt, 32-lane butterfly (codes),
    // then cross-wg combine via LDS packed-u64 keys (round-3 fix) ----
    float cnl[8];
    #pragma unroll
    for (int j = 0; j < 8; j++) cnl[j] = cn[j * 128 + wg * 32 + l31];

    unsigned long long* red = (unsigned long long*)(lds + 32768);
    #pragma unroll
    for (int r = 0; r < 16; r++) {
        float v = 1e30f; int ix = 0;
        #pragma unroll
        for (int j = 0; j < 8; j++) {
            float d = cnl[j] - 2.f * acc[j][r];
            int code = j * 128 + wg * 32 + l31;
            if (d < v) { v = d; ix = code; }   // ascending j keeps lowest idx on ties
        }
        #pragma unroll
        for (int m = 1; m <= 16; m <<= 1) {
            float ov = __shfl_xor(v, m);
            int   oi = __shfl_xor(ix, m);
            if (ov < v || (ov == v && oi < ix)) { v = ov; ix = oi; }
        }
        if (l31 == r) {
            int row = wm * 32 + (r & 3) + 8 * (r >> 2) + 4 * lh;
            uint32_t s = __float_as_uint(v);
            uint32_t k32 = (s & 0x80000000u) ? ~s : (s | 0x80000000u);
            red[wg * 64 + row] = ((unsigned long long)k32 << 32) | (uint32_t)ix;
        }
    }
    __syncthreads();
    if (tid < 64) {
        unsigned long long k0 = red[tid];
        unsigned long long k1 = red[64 + tid];
        unsigned long long k2 = red[128 + tid];
        unsigned long long k3 = red[192 + tid];
        unsigned long long k = k0 < k1 ? k0 : k1;
        if (k2 < k) k = k2;
        if (k3 < k) k = k3;
        bestIdx[n0 + tid] = (uint32_t)k;
    }
}

// ---------------------------------------------------------------------------
// Kernel 3: gather z_q, straight-through output, per-block loss partials.
__global__ void k_gather_loss(const float* __restrict__ z,
                              const float* __restrict__ ct,
                              const uint32_t* __restrict__ bestIdx,
                              float* __restrict__ out,
                              float* __restrict__ pl) {
    int g = blockIdx.x * blockDim.x + threadIdx.x;
    int w4 = g & 1023;
    int bc = g >> 10;
    int c  = bc & 511;
    int b  = bc >> 9;
    int n4 = b * 1024 + w4;

    uint4 iv = *(const uint4*)(bestIdx + (size_t)n4 * 4);

    const float* ctc = ct + (size_t)c * N_E;
    float4 zq;
    zq.x = ctc[iv.x]; zq.y = ctc[iv.y]; zq.z = ctc[iv.z]; zq.w = ctc[iv.w];
    float4 zv = *(const float4*)(z + (size_t)g * 4);

    float4 d;
    d.x = zq.x - zv.x; d.y = zq.y - zv.y; d.z = zq.z - zv.z; d.w = zq.w - zv.w;
    float4 o;
    o.x = zv.x + d.x; o.y = zv.y + d.y; o.z = zv.z + d.z; o.w = zv.w + d.w;
    *(float4*)(out + (size_t)g * 4) = o;

    float ls = d.x * d.x + d.y * d.y + d.z * d.z + d.w * d.w;
    #pragma unroll
    for (int m = 32; m >= 1; m >>= 1) ls += __shfl_xor(ls, m);

    __shared__ float wsum[4];
    int lane = threadIdx.x & 63, wvid = threadIdx.x >> 6;
    if (lane == 0) wsum[wvid] = ls;
    __syncthreads();
    if (threadIdx.x == 0)
        pl[blockIdx.x] = wsum[0] + wsum[1] + wsum[2] + wsum[3];

    if (c == 0) {
        float* ip = out + IDX_OFF + (size_t)n4 * 4;
        ip[0] = (float)iv.x; ip[1] = (float)iv.y;
        ip[2] = (float)iv.z; ip[3] = (float)iv.w;
    }
}

// ---------------------------------------------------------------------------
// Kernel 4: reduce 8192 partials -> loss
__global__ void k_final(const float* __restrict__ pl, float* __restrict__ out) {
    float s = 0.f;
    for (int i = threadIdx.x; i < 8192; i += 256) s += pl[i];
    #pragma unroll
    for (int m = 32; m >= 1; m >>= 1) s += __shfl_xor(s, m);
    __shared__ float wsum[4];
    int lane = threadIdx.x & 63, wvid = threadIdx.x >> 6;
    if (lane == 0) wsum[wvid] = s;
    __syncthreads();
    if (threadIdx.x == 0) {
        float tot = wsum[0] + wsum[1] + wsum[2] + wsum[3];
        out[LOSS_OFF] = 1.25f * tot / (float)ZQ_SIZE;
    }
}

// ---------------------------------------------------------------------------
extern "C" void kernel_launch(void* const* d_in, const int* in_sizes, int n_in,
                              void* d_out, int out_size, void* d_ws, size_t ws_size,
                              hipStream_t stream) {
    (void)in_sizes; (void)n_in; (void)out_size; (void)ws_size;
    const float* z  = (const float*)d_in[0];
    const float* cb = (const float*)d_in[1];
    float* out = (float*)d_out;

    // Workspace: 2.39 MiB total (proven available).
    float* cn = (float*)d_ws + 16;                       // 1024 f   (4 KiB)
    float* ct = cn + 1024;                               // 512x1024 f (2 MiB)
    uint32_t* bestIdx = (uint32_t*)(ct + 512 * 1024);    // 65536 u32 (256 KiB)
    float* pl = (float*)(bestIdx + NROW);                // 8192 f   (32 KiB)

    // Pre-packed codebook tiles (2 MiB) live in the FIRST 2 MiB of d_out:
    // written by k_pack, consumed by k_argmin, then overwritten by k_gather.
    uint32_t* cbP = (uint32_t*)d_out;

    k_pack<<<640, 256, 0, stream>>>(cb, cbP, cn, ct);
    k_argmin_mfma<<<1024, 512, 0, stream>>>(z, cbP, cn, bestIdx);
    k_gather_loss<<<ZQ_SIZE / 4 / 256, 256, 0, stream>>>(z, ct, bestIdx, out, pl);
    k_final<<<1, 256, 0, stream>>>(pl, out);
}